// Round 4
// baseline (309.091 us; speedup 1.0000x reference)
//
#include <hip/hip_runtime.h>
#include <cmath>

#define NODES 40000
#define EDGES 600000
#define HD    128
#define CAP   80            // bucket capacity (Poisson mean 15; P(>80) ~ 0)
#define BN_EPS 1e-5f

typedef short bf16x8 __attribute__((ext_vector_type(8)));
typedef float f32x4  __attribute__((ext_vector_type(4)));
typedef unsigned short u16;
typedef unsigned int   u32;

__device__ __forceinline__ float bf2f(u16 u) {
  union { u32 i; float f; } v; v.i = ((u32)u) << 16; return v.f;
}
__device__ __forceinline__ u16 f2bf(float f) {
  union { float f; u32 i; } v; v.f = f;
  u32 r = v.i + 0x7FFF + ((v.i >> 16) & 1);   // RNE
  return (u16)(r >> 16);
}
// ELU via hardware exp (v_exp_f32): ~5 VALU insts vs ~45 for expm1f.
__device__ __forceinline__ float elu(float x) {
  return x > 0.f ? x : __expf(x) - 1.f;
}

struct WPrep { const float* s[8]; u16* d[8]; };

// ---------------- one-time prep: cast x | transpose weights | zero cnt -----
__global__ __launch_bounds__(256) void prep_all(const float4* __restrict__ x4,
                                                ushort4* __restrict__ xb4,
                                                WPrep p, int* __restrict__ cnt) {
  const int bid = blockIdx.x;
  const int tid = threadIdx.x;
  if (bid < 5000) {
    int i = bid * 256 + tid;
    float4 v = x4[i];
    ushort4 o;
    o.x = f2bf(v.x); o.y = f2bf(v.y); o.z = f2bf(v.z); o.w = f2bf(v.w);
    xb4[i] = o;
  } else if (bid < 5128) {
    int b = bid - 5000;
    int m = b >> 4, xx = b & 15;
    int N = (m == 7) ? 64 : 128;
    int tiles_n = N / 32;
    int tx = xx % tiles_n, tk = xx / tiles_n;
    if (tk >= 4) return;
    __shared__ float t[32][33];
    int c = tid & 31, r8 = tid >> 5;
    const float* s = p.s[m];
    for (int rr = 0; rr < 32; rr += 8)
      t[rr + r8][c] = s[(size_t)(tk * 32 + rr + r8) * N + tx * 32 + c];
    __syncthreads();
    u16* d = p.d[m];
    for (int rr = 0; rr < 32; rr += 8)
      d[(size_t)(tx * 32 + rr + r8) * HD + tk * 32 + c] = f2bf(t[c][rr + r8]);
  } else {
    int i = (bid - 5128) * 256 + tid;
    if (i < NODES) cnt[i] = 0;
  }
}

// ---------------- bucket fill ----------------
__global__ __launch_bounds__(256) void bucket_fill(const int* __restrict__ ei,
                                                   int* __restrict__ cnt,
                                                   int* __restrict__ bucket) {
  int e = blockIdx.x * 256 + threadIdx.x;
  if (e >= EDGES) return;
  int s = ei[e];
  int d = ei[EDGES + e];
  int pos = atomicAdd(&cnt[d], 1);
  if (pos < CAP) bucket[d * CAP + pos] = s;
}

// ------- feature-sliced gather: quarter q covers dims [q*32, q*32+32) -------
// R3 theory: full-row gather (256B = 4 lines/edge) misses the 4MB per-XCD L2
// (10.2MB table, 63% hit) -> lines-in-flight x ~500cyc latency = ~40us/layer.
// Slicing by 32-dim quarters makes each pass's working set 2.56MB (L2-resident
// per XCD) -> ~200cyc L2-hit latency. Same total lines (1/edge/pass x 4), but
// ~2.5x lower latency. Quarter-major grid (bid/5000 = q) gives soft phase
// separation: resident block window << 5000, so one slice is hot at a time.
// Accumulation order per dim identical to the full-row version (bit-exact).
__global__ __launch_bounds__(256) void gather_q(const u16* __restrict__ x,
                                                const int* __restrict__ cnt,
                                                const int* __restrict__ bucket,
                                                u16* __restrict__ agg) {
  const int bid = blockIdx.x;          // 0..19999, quarter-major
  const int q   = bid / 5000;
  const int nb  = bid - q * 5000;
  const int tid = threadIdx.x;
  const int half = (tid >> 5) & 1;
  const int hl = tid & 31;
  const int node = nb * 8 + (tid >> 6) * 2 + half;
  const int i0 = node * CAP;
  const int base = q * 32 + hl;        // this lane's feature dim

  // independent loads issued before any use
  u16 selfv = x[(size_t)node * HD + base];
  int sv = bucket[i0 + hl];            // chunk-0 slots, no cnt dependence
  int deg = cnt[node];
  if (deg > CAP) deg = CAP;
  float a = bf2f(selfv);

  for (int c0 = 0; c0 < deg; c0 += 32) {
    int m = deg - c0;
    if (m > 32) m = 32;
    for (int j = 0; j < m; j += 8) {
      int idx[8];
      u16 uu[8];
#pragma unroll
      for (int jj = 0; jj < 8; ++jj) {
        int src = j + jj < m ? j + jj : 0;
        idx[jj] = __shfl(sv, src, 32);
      }
#pragma unroll
      for (int jj = 0; jj < 8; ++jj)
        uu[jj] = x[(size_t)idx[jj] * HD + base];
#pragma unroll
      for (int jj = 0; jj < 8; ++jj)
        if (j + jj < m) a += bf2f(uu[jj]);
    }
    int nc = c0 + 32;                  // rare next chunk (deg>32); CAP clamp
    if (nc < deg) {
      int ad = nc + hl;
      sv = bucket[i0 + (ad < CAP ? ad : 0)];
    }
  }
  agg[(size_t)node * HD + base] = f2bf(a);
}

// ---------------- fused MLP (layers 1-2) ----------------
// ELU(BN(A@W1+b1)) @ W2 + b2, ELU -> bf16 out.
// LDS rows 0-127: weight (W1, then W2 re-staged); rows 128-191: H strips.
__global__ __launch_bounds__(256) void mlp_fused(
    const u16* __restrict__ A, const u16* __restrict__ W1t,
    const float* __restrict__ b1, const float* __restrict__ g,
    const float* __restrict__ bt, const float* __restrict__ mu,
    const float* __restrict__ vr, const u16* __restrict__ W2t,
    const float* __restrict__ b2, u16* __restrict__ out) {
  constexpr int PK = HD + 8;
  __shared__ u16 L[192][PK];   // 52224 B -> 3 blocks/CU

  const int tid = threadIdx.x;
  const int wv = tid >> 6, lane = tid & 63;
  const int col = lane & 15, kg = lane >> 4;

#pragma unroll
  for (int t = tid; t < 128 * 16; t += 256) {
    int r = t >> 4, c8 = t & 15;
    *(bf16x8*)&L[r][c8 * 8] = *(const bf16x8*)(W1t + (size_t)r * HD + c8 * 8);
  }
  __syncthreads();

  const int strip = blockIdx.x * 4 + wv;
  const u16* Arow = A + (size_t)(strip * 16 + col) * HD;
  const int hrow = 128 + wv * 16;

  // GEMM1
  f32x4 acc[8];
#pragma unroll
  for (int t = 0; t < 8; ++t) acc[t] = (f32x4){0.f, 0.f, 0.f, 0.f};
#pragma unroll
  for (int kk = 0; kk < HD; kk += 32) {
    bf16x8 av = *(const bf16x8*)(Arow + kk + kg * 8);
#pragma unroll
    for (int t = 0; t < 8; ++t) {
      bf16x8 bv = *(const bf16x8*)&L[t * 16 + col][kk + kg * 8];
      acc[t] = __builtin_amdgcn_mfma_f32_16x16x32_bf16(av, bv, acc[t], 0, 0, 0);
    }
  }
  __syncthreads();  // all waves done reading W1

  // stage W2 into rows 0-127; write H (BN+ELU) into own strip
#pragma unroll
  for (int t = tid; t < 128 * 16; t += 256) {
    int r = t >> 4, c8 = t & 15;
    *(bf16x8*)&L[r][c8 * 8] = *(const bf16x8*)(W2t + (size_t)r * HD + c8 * 8);
  }
#pragma unroll
  for (int t = 0; t < 8; ++t) {
    int c = t * 16 + col;
    float rs = rsqrtf(vr[c] + BN_EPS) * g[c];
    float bb = bt[c] + (b1[c] - mu[c]) * rs;
#pragma unroll
    for (int r = 0; r < 4; ++r)
      L[hrow + kg * 4 + r][c] = f2bf(elu(acc[t][r] * rs + bb));
  }
  __syncthreads();

  // GEMM2
  f32x4 acc2[8];
#pragma unroll
  for (int t = 0; t < 8; ++t) acc2[t] = (f32x4){0.f, 0.f, 0.f, 0.f};
#pragma unroll
  for (int kk = 0; kk < HD; kk += 32) {
    bf16x8 av = *(const bf16x8*)&L[hrow + col][kk + kg * 8];
#pragma unroll
    for (int t = 0; t < 8; ++t) {
      bf16x8 bv = *(const bf16x8*)&L[t * 16 + col][kk + kg * 8];
      acc2[t] = __builtin_amdgcn_mfma_f32_16x16x32_bf16(av, bv, acc2[t], 0, 0, 0);
    }
  }
#pragma unroll
  for (int t = 0; t < 8; ++t) {
    int c = t * 16 + col;
    float bb = b2[c];
#pragma unroll
    for (int r = 0; r < 4; ++r)
      L[hrow + kg * 4 + r][c] = f2bf(elu(acc2[t][r] + bb));
  }
  {
    int r0 = lane >> 4, seg = lane & 15;
#pragma unroll
    for (int rr = 0; rr < 16; rr += 4) {
      int row = rr + r0;
      *(float4*)((char*)(out + (size_t)(strip * 16 + row) * HD) + seg * 16) =
          *(const float4*)((const char*)&L[hrow + row][0] + seg * 16);
    }
  }
}

// ------- layer-3 MLP + head: 4 chained GEMMs, all B staged in LDS ----------
__global__ __launch_bounds__(256) void mlp3_head(
    const u16* __restrict__ A, const u16* __restrict__ W1t,
    const float* __restrict__ b1, const float* __restrict__ g,
    const float* __restrict__ bt, const float* __restrict__ mu,
    const float* __restrict__ vr, const u16* __restrict__ W2t,
    const float* __restrict__ b2, const u16* __restrict__ L1t,
    const float* __restrict__ lb1, const u16* __restrict__ L2t,
    const float* __restrict__ lb2, float* __restrict__ out) {
  constexpr int PK = HD + 8;
  __shared__ u16 L[192][PK];

  const int tid = threadIdx.x;
  const int wv = tid >> 6, lane = tid & 63;
  const int col = lane & 15, kg = lane >> 4;

#pragma unroll
  for (int t = tid; t < 128 * 16; t += 256) {
    int r = t >> 4, c8 = t & 15;
    *(bf16x8*)&L[r][c8 * 8] = *(const bf16x8*)(W1t + (size_t)r * HD + c8 * 8);
  }
  __syncthreads();

  const int strip = blockIdx.x * 4 + wv;
  const u16* Arow = A + (size_t)(strip * 16 + col) * HD;
  const int hrow = 128 + wv * 16;

  // GEMM1 (BN+ELU)
  f32x4 acc[8];
#pragma unroll
  for (int t = 0; t < 8; ++t) acc[t] = (f32x4){0.f, 0.f, 0.f, 0.f};
#pragma unroll
  for (int kk = 0; kk < HD; kk += 32) {
    bf16x8 av = *(const bf16x8*)(Arow + kk + kg * 8);
#pragma unroll
    for (int t = 0; t < 8; ++t) {
      bf16x8 bv = *(const bf16x8*)&L[t * 16 + col][kk + kg * 8];
      acc[t] = __builtin_amdgcn_mfma_f32_16x16x32_bf16(av, bv, acc[t], 0, 0, 0);
    }
  }
  __syncthreads();
#pragma unroll
  for (int t = tid; t < 128 * 16; t += 256) {   // stage W2
    int r = t >> 4, c8 = t & 15;
    *(bf16x8*)&L[r][c8 * 8] = *(const bf16x8*)(W2t + (size_t)r * HD + c8 * 8);
  }
#pragma unroll
  for (int t = 0; t < 8; ++t) {
    int c = t * 16 + col;
    float rs = rsqrtf(vr[c] + BN_EPS) * g[c];
    float bb = bt[c] + (b1[c] - mu[c]) * rs;
#pragma unroll
    for (int r = 0; r < 4; ++r)
      L[hrow + kg * 4 + r][c] = f2bf(elu(acc[t][r] * rs + bb));
  }
  __syncthreads();

  // GEMM2 (+b2, ELU)
#pragma unroll
  for (int t = 0; t < 8; ++t) acc[t] = (f32x4){0.f, 0.f, 0.f, 0.f};
#pragma unroll
  for (int kk = 0; kk < HD; kk += 32) {
    bf16x8 av = *(const bf16x8*)&L[hrow + col][kk + kg * 8];
#pragma unroll
    for (int t = 0; t < 8; ++t) {
      bf16x8 bv = *(const bf16x8*)&L[t * 16 + col][kk + kg * 8];
      acc[t] = __builtin_amdgcn_mfma_f32_16x16x32_bf16(av, bv, acc[t], 0, 0, 0);
    }
  }
  __syncthreads();
#pragma unroll
  for (int t = tid; t < 128 * 16; t += 256) {   // stage lin1
    int r = t >> 4, c8 = t & 15;
    *(bf16x8*)&L[r][c8 * 8] = *(const bf16x8*)(L1t + (size_t)r * HD + c8 * 8);
  }
#pragma unroll
  for (int t = 0; t < 8; ++t) {
    int c = t * 16 + col;
    float bb = b2[c];
#pragma unroll
    for (int r = 0; r < 4; ++r)
      L[hrow + kg * 4 + r][c] = f2bf(elu(acc[t][r] + bb));
  }
  __syncthreads();

  // LIN1 (+lb1, ELU)
#pragma unroll
  for (int t = 0; t < 8; ++t) acc[t] = (f32x4){0.f, 0.f, 0.f, 0.f};
#pragma unroll
  for (int kk = 0; kk < HD; kk += 32) {
    bf16x8 av = *(const bf16x8*)&L[hrow + col][kk + kg * 8];
#pragma unroll
    for (int t = 0; t < 8; ++t) {
      bf16x8 bv = *(const bf16x8*)&L[t * 16 + col][kk + kg * 8];
      acc[t] = __builtin_amdgcn_mfma_f32_16x16x32_bf16(av, bv, acc[t], 0, 0, 0);
    }
  }
  __syncthreads();
#pragma unroll
  for (int t = tid; t < 64 * 16; t += 256) {    // stage lin2 (64 rows)
    int r = t >> 4, c8 = t & 15;
    *(bf16x8*)&L[r][c8 * 8] = *(const bf16x8*)(L2t + (size_t)r * HD + c8 * 8);
  }
#pragma unroll
  for (int t = 0; t < 8; ++t) {
    int c = t * 16 + col;
    float bb = lb1[c];
#pragma unroll
    for (int r = 0; r < 4; ++r)
      L[hrow + kg * 4 + r][c] = f2bf(elu(acc[t][r] + bb));
  }
  __syncthreads();

  // LIN2 (+lb2) -> fp32 out [.][64]
  f32x4 acc2[4];
#pragma unroll
  for (int t = 0; t < 4; ++t) acc2[t] = (f32x4){0.f, 0.f, 0.f, 0.f};
#pragma unroll
  for (int kk = 0; kk < HD; kk += 32) {
    bf16x8 av = *(const bf16x8*)&L[hrow + col][kk + kg * 8];
#pragma unroll
    for (int t = 0; t < 4; ++t) {
      bf16x8 bv = *(const bf16x8*)&L[t * 16 + col][kk + kg * 8];
      acc2[t] = __builtin_amdgcn_mfma_f32_16x16x32_bf16(av, bv, acc2[t], 0, 0, 0);
    }
  }
#pragma unroll
  for (int t = 0; t < 4; ++t) {
    int c = t * 16 + col;
    float bb = lb2[c];
#pragma unroll
    for (int r = 0; r < 4; ++r)
      ((float*)&L[hrow + kg * 4 + r][0])[c] = acc2[t][r] + bb;
  }
  {
    int r0 = lane >> 4, seg = lane & 15;
#pragma unroll
    for (int rr = 0; rr < 16; rr += 4) {
      int row = rr + r0;
      *(float4*)((char*)(out + (size_t)(strip * 16 + row) * 64) + seg * 16) =
          *(const float4*)((const char*)&L[hrow + row][0] + seg * 16);
    }
  }
}

extern "C" void kernel_launch(void* const* d_in, const int* in_sizes, int n_in,
                              void* d_out, int out_size, void* d_ws, size_t ws_size,
                              hipStream_t stream) {
  const float* x = (const float*)d_in[0];
  const int* ei  = (const int*)d_in[1];
  const float* p[30];
  for (int i = 0; i < 30 && i < n_in; ++i) p[i] = (const float*)d_in[i];

  const size_t FEAT = (size_t)NODES * HD;
  u16* xb   = (u16*)d_ws;
  u16* tmp  = xb + FEAT;
  u16* wt   = tmp + FEAT;
  u16* wts[8];
  for (int m = 0; m < 8; ++m) wts[m] = wt + (size_t)m * HD * HD;
  int* cnt    = (int*)(wt + 8 * HD * HD);
  int* bucket = cnt + NODES;

  dim3 blk(256);
  const int edgeGrid = (EDGES + 255) / 256;   // 2344
  const int gathGrid = 4 * (NODES / 8);       // 20000, quarter-major
  const int gemmGrid = NODES / 64;            // 625

  WPrep wp;
  const int widx[8] = {2, 8, 10, 16, 18, 24, 26, 28};
  for (int m = 0; m < 8; ++m) { wp.s[m] = p[widx[m]]; wp.d[m] = wts[m]; }
  prep_all<<<5285, blk, 0, stream>>>((const float4*)x, (ushort4*)xb, wp, cnt);
  bucket_fill<<<edgeGrid, blk, 0, stream>>>(ei, cnt, bucket);

  for (int l = 0; l < 2; ++l) {
    const int base = 2 + l * 8;
    gather_q<<<gathGrid, blk, 0, stream>>>(xb, cnt, bucket, tmp);
    mlp_fused<<<gemmGrid, blk, 0, stream>>>(
        tmp, wts[l * 2], p[base + 1], p[base + 2], p[base + 3], p[base + 4],
        p[base + 5], wts[l * 2 + 1], p[base + 7], xb);
  }
  gather_q<<<gathGrid, blk, 0, stream>>>(xb, cnt, bucket, tmp);
  mlp3_head<<<gemmGrid, blk, 0, stream>>>(
      tmp, wts[4], p[19], p[20], p[21], p[22], p[23], wts[5], p[25],
      wts[6], p[27], wts[7], p[29], (float*)d_out);
}

// Round 6
// 264.387 us; speedup vs baseline: 1.1691x; 1.1691x over previous
//
#include <hip/hip_runtime.h>
#include <hip/hip_cooperative_groups.h>
#include <cmath>

namespace cg = cooperative_groups;

#define NODES 40000
#define NPAD  40960            // padded rows so MLP strips are uniform
#define EDGES 600000
#define HD    128
#define CAP   80               // bucket capacity (Poisson mean 15; P(>80) ~ 0)
#define BN_EPS 1e-5f
#define PK    (HD + 8)
#define GRID  256              // 1 block/CU -> co-residency guaranteed
#define BLK   1024             // 16 waves/CU for gather MLP-parallelism
#define SPB   10               // strips per block: 256*10 = 2560 = NPAD/16

typedef short bf16x8 __attribute__((ext_vector_type(8)));
typedef float f32x4  __attribute__((ext_vector_type(4)));
typedef unsigned short u16;
typedef unsigned int   u32;

__device__ __forceinline__ float bf2f(u16 u) {
  union { u32 i; float f; } v; v.i = ((u32)u) << 16; return v.f;
}
__device__ __forceinline__ u16 f2bf(float f) {
  union { float f; u32 i; } v; v.f = f;
  u32 r = v.i + 0x7FFF + ((v.i >> 16) & 1);   // RNE
  return (u16)(r >> 16);
}
__device__ __forceinline__ float elu(float x) {
  return x > 0.f ? x : __expf(x) - 1.f;
}

struct Params {
  const float* x; const int* ei;
  const float* ws[8]; u16* wd[8];
  const float* b1[3]; const float* gg[3]; const float* bt[3];
  const float* mu[3]; const float* vr[3]; const float* b2[3];
  const float* lb1; const float* lb2;
  u16* xb; u16* tmp; int* cnt; int* bucket; float* out;
};

// ---- gather: per-half-wave node loop (R2-verified body) -------------------
__device__ __forceinline__ void gather_phase(const u16* __restrict__ x,
                                             const int* __restrict__ cnt,
                                             const int* __restrict__ bucket,
                                             u16* __restrict__ agg,
                                             int hw, int nhw) {
  const int hl = threadIdx.x & 31;
  for (int node = hw; node < NODES; node += nhw) {
    const int i0 = node * CAP;
    uint2 self = ((const uint2*)(x + (size_t)node * HD))[hl];
    int sv = bucket[i0 + hl];          // chunk-0 slots, no cnt dependence
    int deg = cnt[node];
    if (deg > CAP) deg = CAP;
    float a0 = bf2f((u16)self.x), a1 = bf2f((u16)(self.x >> 16));
    float a2 = bf2f((u16)self.y), a3 = bf2f((u16)(self.y >> 16));
    for (int c0 = 0; c0 < deg; c0 += 32) {
      int m = deg - c0;
      if (m > 32) m = 32;
      for (int j = 0; j < m; j += 8) {
        int idx[8];
        uint2 uu[8];
#pragma unroll
        for (int jj = 0; jj < 8; ++jj) {
          int src = j + jj < m ? j + jj : 0;
          idx[jj] = __shfl(sv, src, 32);
        }
#pragma unroll
        for (int jj = 0; jj < 8; ++jj)
          uu[jj] = ((const uint2*)(x + (size_t)idx[jj] * HD))[hl];
#pragma unroll
        for (int jj = 0; jj < 8; ++jj) {
          if (j + jj < m) {
            a0 += bf2f((u16)uu[jj].x);
            a1 += bf2f((u16)(uu[jj].x >> 16));
            a2 += bf2f((u16)uu[jj].y);
            a3 += bf2f((u16)(uu[jj].y >> 16));
          }
        }
      }
      int nc = c0 + 32;                // rare next chunk (deg>32); CAP clamp
      if (nc < deg) {
        int a = nc + hl;
        sv = bucket[i0 + (a < CAP ? a : 0)];
      }
    }
    uint2 pk;
    pk.x = (u32)f2bf(a0) | ((u32)f2bf(a1) << 16);
    pk.y = (u32)f2bf(a2) | ((u32)f2bf(a3) << 16);
    ((uint2*)(agg + (size_t)node * HD))[hl] = pk;
  }
}

// ---- 2-GEMM MLP phase (R2-verified math); waves wv<SPB active -------------
__device__ __forceinline__ void mlp2_phase(u16 (*L)[PK],
    const u16* __restrict__ A, const u16* __restrict__ W1t,
    const float* __restrict__ b1, const float* __restrict__ g,
    const float* __restrict__ bt, const float* __restrict__ mu,
    const float* __restrict__ vr, const u16* __restrict__ W2t,
    const float* __restrict__ b2, u16* __restrict__ out, int tid, int bid) {
  const int wv = tid >> 6, lane = tid & 63;
  const int col = lane & 15, kg = lane >> 4;
  const bool act = (wv < SPB);
  const int strip = bid * SPB + wv;    // < 2560 when act
  const int hrow = 128 + wv * 16;

  for (int t = tid; t < 128 * 16; t += BLK) {
    int r = t >> 4, c8 = t & 15;
    *(bf16x8*)&L[r][c8 * 8] = *(const bf16x8*)(W1t + (size_t)r * HD + c8 * 8);
  }
  __syncthreads();

  f32x4 acc[8];
#pragma unroll
  for (int t = 0; t < 8; ++t) acc[t] = (f32x4){0.f, 0.f, 0.f, 0.f};
  if (act) {
    const u16* Arow = A + (size_t)(strip * 16 + col) * HD;
#pragma unroll
    for (int kk = 0; kk < HD; kk += 32) {
      bf16x8 av = *(const bf16x8*)(Arow + kk + kg * 8);
#pragma unroll
      for (int t = 0; t < 8; ++t) {
        bf16x8 bv = *(const bf16x8*)&L[t * 16 + col][kk + kg * 8];
        acc[t] = __builtin_amdgcn_mfma_f32_16x16x32_bf16(av, bv, acc[t], 0, 0, 0);
      }
    }
  }
  __syncthreads();  // all waves done reading W1

  for (int t = tid; t < 128 * 16; t += BLK) {   // stage W2
    int r = t >> 4, c8 = t & 15;
    *(bf16x8*)&L[r][c8 * 8] = *(const bf16x8*)(W2t + (size_t)r * HD + c8 * 8);
  }
  if (act) {
#pragma unroll
    for (int t = 0; t < 8; ++t) {
      int c = t * 16 + col;
      float rs = rsqrtf(vr[c] + BN_EPS) * g[c];
      float bb = bt[c] + (b1[c] - mu[c]) * rs;
#pragma unroll
      for (int r = 0; r < 4; ++r)
        L[hrow + kg * 4 + r][c] = f2bf(elu(acc[t][r] * rs + bb));
    }
  }
  __syncthreads();

  f32x4 acc2[8];
#pragma unroll
  for (int t = 0; t < 8; ++t) acc2[t] = (f32x4){0.f, 0.f, 0.f, 0.f};
  if (act) {
#pragma unroll
    for (int kk = 0; kk < HD; kk += 32) {
      bf16x8 av = *(const bf16x8*)&L[hrow + col][kk + kg * 8];
#pragma unroll
      for (int t = 0; t < 8; ++t) {
        bf16x8 bv = *(const bf16x8*)&L[t * 16 + col][kk + kg * 8];
        acc2[t] = __builtin_amdgcn_mfma_f32_16x16x32_bf16(av, bv, acc2[t], 0, 0, 0);
      }
    }
#pragma unroll
    for (int t = 0; t < 8; ++t) {
      int c = t * 16 + col;
      float bb = b2[c];
#pragma unroll
      for (int r = 0; r < 4; ++r)
        L[hrow + kg * 4 + r][c] = f2bf(elu(acc2[t][r] + bb));
    }
    int r0 = lane >> 4, seg = lane & 15;
#pragma unroll
    for (int rr = 0; rr < 16; rr += 4) {
      int row = rr + r0;
      *(float4*)((char*)(out + (size_t)(strip * 16 + row) * HD) + seg * 16) =
          *(const float4*)((const char*)&L[hrow + row][0] + seg * 16);
    }
  }
}

// ---- layer-3 MLP + head phase (R2-verified math) --------------------------
__device__ __forceinline__ void head_phase(u16 (*L)[PK],
    const u16* __restrict__ A, const u16* __restrict__ W1t,
    const float* __restrict__ b1, const float* __restrict__ g,
    const float* __restrict__ bt, const float* __restrict__ mu,
    const float* __restrict__ vr, const u16* __restrict__ W2t,
    const float* __restrict__ b2, const u16* __restrict__ L1t,
    const float* __restrict__ lb1, const u16* __restrict__ L2t,
    const float* __restrict__ lb2, float* __restrict__ out, int tid, int bid) {
  const int wv = tid >> 6, lane = tid & 63;
  const int col = lane & 15, kg = lane >> 4;
  const bool act = (wv < SPB);
  const int strip = bid * SPB + wv;
  const int hrow = 128 + wv * 16;

  for (int t = tid; t < 128 * 16; t += BLK) {
    int r = t >> 4, c8 = t & 15;
    *(bf16x8*)&L[r][c8 * 8] = *(const bf16x8*)(W1t + (size_t)r * HD + c8 * 8);
  }
  __syncthreads();

  f32x4 acc[8];
#pragma unroll
  for (int t = 0; t < 8; ++t) acc[t] = (f32x4){0.f, 0.f, 0.f, 0.f};
  if (act) {
    const u16* Arow = A + (size_t)(strip * 16 + col) * HD;
#pragma unroll
    for (int kk = 0; kk < HD; kk += 32) {
      bf16x8 av = *(const bf16x8*)(Arow + kk + kg * 8);
#pragma unroll
      for (int t = 0; t < 8; ++t) {
        bf16x8 bv = *(const bf16x8*)&L[t * 16 + col][kk + kg * 8];
        acc[t] = __builtin_amdgcn_mfma_f32_16x16x32_bf16(av, bv, acc[t], 0, 0, 0);
      }
    }
  }
  __syncthreads();
  for (int t = tid; t < 128 * 16; t += BLK) {   // stage W2
    int r = t >> 4, c8 = t & 15;
    *(bf16x8*)&L[r][c8 * 8] = *(const bf16x8*)(W2t + (size_t)r * HD + c8 * 8);
  }
  if (act) {
#pragma unroll
    for (int t = 0; t < 8; ++t) {
      int c = t * 16 + col;
      float rs = rsqrtf(vr[c] + BN_EPS) * g[c];
      float bb = bt[c] + (b1[c] - mu[c]) * rs;
#pragma unroll
      for (int r = 0; r < 4; ++r)
        L[hrow + kg * 4 + r][c] = f2bf(elu(acc[t][r] * rs + bb));
    }
  }
  __syncthreads();

#pragma unroll
  for (int t = 0; t < 8; ++t) acc[t] = (f32x4){0.f, 0.f, 0.f, 0.f};
  if (act) {
#pragma unroll
    for (int kk = 0; kk < HD; kk += 32) {
      bf16x8 av = *(const bf16x8*)&L[hrow + col][kk + kg * 8];
#pragma unroll
      for (int t = 0; t < 8; ++t) {
        bf16x8 bv = *(const bf16x8*)&L[t * 16 + col][kk + kg * 8];
        acc[t] = __builtin_amdgcn_mfma_f32_16x16x32_bf16(av, bv, acc[t], 0, 0, 0);
      }
    }
  }
  __syncthreads();
  for (int t = tid; t < 128 * 16; t += BLK) {   // stage lin1
    int r = t >> 4, c8 = t & 15;
    *(bf16x8*)&L[r][c8 * 8] = *(const bf16x8*)(L1t + (size_t)r * HD + c8 * 8);
  }
  if (act) {
#pragma unroll
    for (int t = 0; t < 8; ++t) {
      int c = t * 16 + col;
      float bb = b2[c];
#pragma unroll
      for (int r = 0; r < 4; ++r)
        L[hrow + kg * 4 + r][c] = f2bf(elu(acc[t][r] + bb));
    }
  }
  __syncthreads();

#pragma unroll
  for (int t = 0; t < 8; ++t) acc[t] = (f32x4){0.f, 0.f, 0.f, 0.f};
  if (act) {
#pragma unroll
    for (int kk = 0; kk < HD; kk += 32) {
      bf16x8 av = *(const bf16x8*)&L[hrow + col][kk + kg * 8];
#pragma unroll
      for (int t = 0; t < 8; ++t) {
        bf16x8 bv = *(const bf16x8*)&L[t * 16 + col][kk + kg * 8];
        acc[t] = __builtin_amdgcn_mfma_f32_16x16x32_bf16(av, bv, acc[t], 0, 0, 0);
      }
    }
  }
  __syncthreads();
  for (int t = tid; t < 64 * 16; t += BLK) {    // stage lin2 (64 rows)
    int r = t >> 4, c8 = t & 15;
    *(bf16x8*)&L[r][c8 * 8] = *(const bf16x8*)(L2t + (size_t)r * HD + c8 * 8);
  }
  if (act) {
#pragma unroll
    for (int t = 0; t < 8; ++t) {
      int c = t * 16 + col;
      float bb = lb1[c];
#pragma unroll
      for (int r = 0; r < 4; ++r)
        L[hrow + kg * 4 + r][c] = f2bf(elu(acc[t][r] + bb));
    }
  }
  __syncthreads();

  if (act) {
    f32x4 acc2[4];
#pragma unroll
    for (int t = 0; t < 4; ++t) acc2[t] = (f32x4){0.f, 0.f, 0.f, 0.f};
#pragma unroll
    for (int kk = 0; kk < HD; kk += 32) {
      bf16x8 av = *(const bf16x8*)&L[hrow + col][kk + kg * 8];
#pragma unroll
      for (int t = 0; t < 4; ++t) {
        bf16x8 bv = *(const bf16x8*)&L[t * 16 + col][kk + kg * 8];
        acc2[t] = __builtin_amdgcn_mfma_f32_16x16x32_bf16(av, bv, acc2[t], 0, 0, 0);
      }
    }
#pragma unroll
    for (int t = 0; t < 4; ++t) {
      int c = t * 16 + col;
      float bb = lb2[c];
#pragma unroll
      for (int r = 0; r < 4; ++r)
        ((float*)&L[hrow + kg * 4 + r][0])[c] = acc2[t][r] + bb;
    }
    if (strip < NODES / 16) {          // real strips only
      int r0 = lane >> 4, seg = lane & 15;
#pragma unroll
      for (int rr = 0; rr < 16; rr += 4) {
        int row = rr + r0;
        *(float4*)((char*)(out + (size_t)(strip * 16 + row) * 64) + seg * 16) =
            *(const float4*)((const char*)&L[hrow + row][0] + seg * 16);
      }
    }
  }
}

// ------------------- single persistent cooperative kernel ------------------
__global__ __launch_bounds__(BLK, 4) void gin_all(Params P) {
  cg::grid_group grid = cg::this_grid();
  __shared__ u16 L[288][PK];           // 78,336 B; 1 block/CU
  const int tid = threadIdx.x, bid = blockIdx.x;
  const int hw = (bid * BLK + tid) >> 5;
  const int nhw = GRID * BLK / 32;     // 8192 half-waves

  // ---- P0: cast x -> bf16 | zero cnt | transpose weights ----
  {
    const float4* x4 = (const float4*)P.x;
    ushort4* xb4 = (ushort4*)P.xb;
    for (int i = bid * BLK + tid; i < NODES * HD / 4; i += GRID * BLK) {
      float4 v = x4[i];
      ushort4 o;
      o.x = f2bf(v.x); o.y = f2bf(v.y); o.z = f2bf(v.z); o.w = f2bf(v.w);
      xb4[i] = o;
    }
    for (int i = bid * BLK + tid; i < NODES; i += GRID * BLK) P.cnt[i] = 0;
    if (bid < 128) {
      int m = bid >> 4, xx = bid & 15;
      int N = (m == 7) ? 64 : 128;
      int tn = N / 32;
      int tx = xx % tn, tk = xx / tn;
      bool valid = (tk < 4);
      float* tf = (float*)&L[0][0];    // 32x33 f32 scratch
      int c = tid & 31, r8 = tid >> 5;
      if (valid && tid < 256) {
        const float* s = P.ws[m];
        for (int rr = 0; rr < 32; rr += 8)
          tf[(rr + r8) * 33 + c] = s[(size_t)(tk * 32 + rr + r8) * N + tx * 32 + c];
      }
      __syncthreads();
      if (valid && tid < 256) {
        u16* d = P.wd[m];
        for (int rr = 0; rr < 32; rr += 8)
          d[(size_t)(tx * 32 + rr + r8) * HD + tk * 32 + c] = f2bf(tf[c * 33 + rr + r8]);
      }
    }
  }
  __threadfence();
  grid.sync();

  // ---- P1: bucket fill ----
  for (int e = bid * BLK + tid; e < EDGES; e += GRID * BLK) {
    int s = P.ei[e];
    int d = P.ei[EDGES + e];
    int pos = atomicAdd(&P.cnt[d], 1);
    if (pos < CAP) P.bucket[d * CAP + pos] = s;
  }
  __threadfence();
  grid.sync();

  // ---- P2: 3 x (gather -> MLP) ----
  for (int l = 0; l < 3; ++l) {
    gather_phase(P.xb, P.cnt, P.bucket, P.tmp, hw, nhw);
    __threadfence();
    grid.sync();
    if (l < 2)
      mlp2_phase(L, P.tmp, P.wd[2 * l], P.b1[l], P.gg[l], P.bt[l], P.mu[l],
                 P.vr[l], P.wd[2 * l + 1], P.b2[l], P.xb, tid, bid);
    else
      head_phase(L, P.tmp, P.wd[4], P.b1[2], P.gg[2], P.bt[2], P.mu[2],
                 P.vr[2], P.wd[5], P.b2[2], P.wd[6], P.lb1, P.wd[7], P.lb2,
                 P.out, tid, bid);
    if (l < 2) {
      __threadfence();
      grid.sync();
    }
  }
}

// ======================= fallback: R2-verified pipeline ====================
struct WPrep { const float* s[8]; u16* d[8]; };

__global__ __launch_bounds__(256) void prep_all(const float4* __restrict__ x4,
                                                ushort4* __restrict__ xb4,
                                                WPrep p, int* __restrict__ cnt) {
  const int bid = blockIdx.x;
  const int tid = threadIdx.x;
  if (bid < 5000) {
    int i = bid * 256 + tid;
    float4 v = x4[i];
    ushort4 o;
    o.x = f2bf(v.x); o.y = f2bf(v.y); o.z = f2bf(v.z); o.w = f2bf(v.w);
    xb4[i] = o;
  } else if (bid < 5128) {
    int b = bid - 5000;
    int m = b >> 4, xx = b & 15;
    int N = (m == 7) ? 64 : 128;
    int tiles_n = N / 32;
    int tx = xx % tiles_n, tk = xx / tiles_n;
    if (tk >= 4) return;
    __shared__ float t[32][33];
    int c = tid & 31, r8 = tid >> 5;
    const float* s = p.s[m];
    for (int rr = 0; rr < 32; rr += 8)
      t[rr + r8][c] = s[(size_t)(tk * 32 + rr + r8) * N + tx * 32 + c];
    __syncthreads();
    u16* d = p.d[m];
    for (int rr = 0; rr < 32; rr += 8)
      d[(size_t)(tx * 32 + rr + r8) * HD + tk * 32 + c] = f2bf(t[c][rr + r8]);
  } else {
    int i = (bid - 5128) * 256 + tid;
    if (i < NODES) cnt[i] = 0;
  }
}

__global__ __launch_bounds__(256) void bucket_fill(const int* __restrict__ ei,
                                                   int* __restrict__ cnt,
                                                   int* __restrict__ bucket) {
  int e = blockIdx.x * 256 + threadIdx.x;
  if (e >= EDGES) return;
  int s = ei[e];
  int d = ei[EDGES + e];
  int pos = atomicAdd(&cnt[d], 1);
  if (pos < CAP) bucket[d * CAP + pos] = s;
}

__global__ __launch_bounds__(256) void gather_w(const u16* __restrict__ x,
                                                const int* __restrict__ cnt,
                                                const int* __restrict__ bucket,
                                                u16* __restrict__ agg) {
  const int tid = threadIdx.x;
  const int hw = blockIdx.x * 8 + (tid >> 5);
  gather_phase(x, cnt, bucket, agg, hw, NODES + 8);  // single node per hw
}

__global__ __launch_bounds__(256) void mlp_fused_k(
    const u16* __restrict__ A, const u16* __restrict__ W1t,
    const float* __restrict__ b1, const float* __restrict__ g,
    const float* __restrict__ bt, const float* __restrict__ mu,
    const float* __restrict__ vr, const u16* __restrict__ W2t,
    const float* __restrict__ b2, u16* __restrict__ out) {
  __shared__ u16 L[192][PK];
  const int tid = threadIdx.x;
  const int wv = tid >> 6, lane = tid & 63;
  const int col = lane & 15, kg = lane >> 4;
  for (int t = tid; t < 128 * 16; t += 256) {
    int r = t >> 4, c8 = t & 15;
    *(bf16x8*)&L[r][c8 * 8] = *(const bf16x8*)(W1t + (size_t)r * HD + c8 * 8);
  }
  __syncthreads();
  const int strip = blockIdx.x * 4 + wv;
  const u16* Arow = A + (size_t)(strip * 16 + col) * HD;
  const int hrow = 128 + wv * 16;
  f32x4 acc[8];
#pragma unroll
  for (int t = 0; t < 8; ++t) acc[t] = (f32x4){0.f, 0.f, 0.f, 0.f};
#pragma unroll
  for (int kk = 0; kk < HD; kk += 32) {
    bf16x8 av = *(const bf16x8*)(Arow + kk + kg * 8);
#pragma unroll
    for (int t = 0; t < 8; ++t) {
      bf16x8 bv = *(const bf16x8*)&L[t * 16 + col][kk + kg * 8];
      acc[t] = __builtin_amdgcn_mfma_f32_16x16x32_bf16(av, bv, acc[t], 0, 0, 0);
    }
  }
  __syncthreads();
  for (int t = tid; t < 128 * 16; t += 256) {
    int r = t >> 4, c8 = t & 15;
    *(bf16x8*)&L[r][c8 * 8] = *(const bf16x8*)(W2t + (size_t)r * HD + c8 * 8);
  }
#pragma unroll
  for (int t = 0; t < 8; ++t) {
    int c = t * 16 + col;
    float rs = rsqrtf(vr[c] + BN_EPS) * g[c];
    float bb = bt[c] + (b1[c] - mu[c]) * rs;
#pragma unroll
    for (int r = 0; r < 4; ++r)
      L[hrow + kg * 4 + r][c] = f2bf(elu(acc[t][r] * rs + bb));
  }
  __syncthreads();
  f32x4 acc2[8];
#pragma unroll
  for (int t = 0; t < 8; ++t) acc2[t] = (f32x4){0.f, 0.f, 0.f, 0.f};
#pragma unroll
  for (int kk = 0; kk < HD; kk += 32) {
    bf16x8 av = *(const bf16x8*)&L[hrow + col][kk + kg * 8];
#pragma unroll
    for (int t = 0; t < 8; ++t) {
      bf16x8 bv = *(const bf16x8*)&L[t * 16 + col][kk + kg * 8];
      acc2[t] = __builtin_amdgcn_mfma_f32_16x16x32_bf16(av, bv, acc2[t], 0, 0, 0);
    }
  }
#pragma unroll
  for (int t = 0; t < 8; ++t) {
    int c = t * 16 + col;
    float bb = b2[c];
#pragma unroll
    for (int r = 0; r < 4; ++r)
      L[hrow + kg * 4 + r][c] = f2bf(elu(acc2[t][r] + bb));
  }
  {
    int r0 = lane >> 4, seg = lane & 15;
#pragma unroll
    for (int rr = 0; rr < 16; rr += 4) {
      int row = rr + r0;
      *(float4*)((char*)(out + (size_t)(strip * 16 + row) * HD) + seg * 16) =
          *(const float4*)((const char*)&L[hrow + row][0] + seg * 16);
    }
  }
}

__global__ __launch_bounds__(256) void mlp3_head_k(
    const u16* __restrict__ A, const u16* __restrict__ W1t,
    const float* __restrict__ b1, const float* __restrict__ g,
    const float* __restrict__ bt, const float* __restrict__ mu,
    const float* __restrict__ vr, const u16* __restrict__ W2t,
    const float* __restrict__ b2, const u16* __restrict__ L1t,
    const float* __restrict__ lb1, const u16* __restrict__ L2t,
    const float* __restrict__ lb2, float* __restrict__ out) {
  __shared__ u16 L[192][PK];
  const int tid = threadIdx.x;
  const int wv = tid >> 6, lane = tid & 63;
  const int col = lane & 15, kg = lane >> 4;
  for (int t = tid; t < 128 * 16; t += 256) {
    int r = t >> 4, c8 = t & 15;
    *(bf16x8*)&L[r][c8 * 8] = *(const bf16x8*)(W1t + (size_t)r * HD + c8 * 8);
  }
  __syncthreads();
  const int strip = blockIdx.x * 4 + wv;
  const u16* Arow = A + (size_t)(strip * 16 + col) * HD;
  const int hrow = 128 + wv * 16;
  f32x4 acc[8];
#pragma unroll
  for (int t = 0; t < 8; ++t) acc[t] = (f32x4){0.f, 0.f, 0.f, 0.f};
#pragma unroll
  for (int kk = 0; kk < HD; kk += 32) {
    bf16x8 av = *(const bf16x8*)(Arow + kk + kg * 8);
#pragma unroll
    for (int t = 0; t < 8; ++t) {
      bf16x8 bv = *(const bf16x8*)&L[t * 16 + col][kk + kg * 8];
      acc[t] = __builtin_amdgcn_mfma_f32_16x16x32_bf16(av, bv, acc[t], 0, 0, 0);
    }
  }
  __syncthreads();
  for (int t = tid; t < 128 * 16; t += 256) {
    int r = t >> 4, c8 = t & 15;
    *(bf16x8*)&L[r][c8 * 8] = *(const bf16x8*)(W2t + (size_t)r * HD + c8 * 8);
  }
#pragma unroll
  for (int t = 0; t < 8; ++t) {
    int c = t * 16 + col;
    float rs = rsqrtf(vr[c] + BN_EPS) * g[c];
    float bb = bt[c] + (b1[c] - mu[c]) * rs;
#pragma unroll
    for (int r = 0; r < 4; ++r)
      L[hrow + kg * 4 + r][c] = f2bf(elu(acc[t][r] * rs + bb));
  }
  __syncthreads();
#pragma unroll
  for (int t = 0; t < 8; ++t) acc[t] = (f32x4){0.f, 0.f, 0.f, 0.f};
#pragma unroll
  for (int kk = 0; kk < HD; kk += 32) {
    bf16x8 av = *(const bf16x8*)&L[hrow + col][kk + kg * 8];
#pragma unroll
    for (int t = 0; t < 8; ++t) {
      bf16x8 bv = *(const bf16x8*)&L[t * 16 + col][kk + kg * 8];
      acc[t] = __builtin_amdgcn_mfma_f32_16x16x32_bf16(av, bv, acc[t], 0, 0, 0);
    }
  }
  __syncthreads();
  for (int t = tid; t < 128 * 16; t += 256) {
    int r = t >> 4, c8 = t & 15;
    *(bf16x8*)&L[r][c8 * 8] = *(const bf16x8*)(L1t + (size_t)r * HD + c8 * 8);
  }
#pragma unroll
  for (int t = 0; t < 8; ++t) {
    int c = t * 16 + col;
    float bb = b2[c];
#pragma unroll
    for (int r = 0; r < 4; ++r)
      L[hrow + kg * 4 + r][c] = f2bf(elu(acc[t][r] + bb));
  }
  __syncthreads();
#pragma unroll
  for (int t = 0; t < 8; ++t) acc[t] = (f32x4){0.f, 0.f, 0.f, 0.f};
#pragma unroll
  for (int kk = 0; kk < HD; kk += 32) {
    bf16x8 av = *(const bf16x8*)&L[hrow + col][kk + kg * 8];
#pragma unroll
    for (int t = 0; t < 8; ++t) {
      bf16x8 bv = *(const bf16x8*)&L[t * 16 + col][kk + kg * 8];
      acc[t] = __builtin_amdgcn_mfma_f32_16x16x32_bf16(av, bv, acc[t], 0, 0, 0);
    }
  }
  __syncthreads();
  for (int t = tid; t < 64 * 16; t += 256) {
    int r = t >> 4, c8 = t & 15;
    *(bf16x8*)&L[r][c8 * 8] = *(const bf16x8*)(L2t + (size_t)r * HD + c8 * 8);
  }
#pragma unroll
  for (int t = 0; t < 8; ++t) {
    int c = t * 16 + col;
    float bb = lb1[c];
#pragma unroll
    for (int r = 0; r < 4; ++r)
      L[hrow + kg * 4 + r][c] = f2bf(elu(acc[t][r] + bb));
  }
  __syncthreads();
  f32x4 acc2[4];
#pragma unroll
  for (int t = 0; t < 4; ++t) acc2[t] = (f32x4){0.f, 0.f, 0.f, 0.f};
#pragma unroll
  for (int kk = 0; kk < HD; kk += 32) {
    bf16x8 av = *(const bf16x8*)&L[hrow + col][kk + kg * 8];
#pragma unroll
    for (int t = 0; t < 4; ++t) {
      bf16x8 bv = *(const bf16x8*)&L[t * 16 + col][kk + kg * 8];
      acc2[t] = __builtin_amdgcn_mfma_f32_16x16x32_bf16(av, bv, acc2[t], 0, 0, 0);
    }
  }
#pragma unroll
  for (int t = 0; t < 4; ++t) {
    int c = t * 16 + col;
    float bb = lb2[c];
#pragma unroll
    for (int r = 0; r < 4; ++r)
      ((float*)&L[hrow + kg * 4 + r][0])[c] = acc2[t][r] + bb;
  }
  {
    int r0 = lane >> 4, seg = lane & 15;
#pragma unroll
    for (int rr = 0; rr < 16; rr += 4) {
      int row = rr + r0;
      *(float4*)((char*)(out + (size_t)(strip * 16 + row) * 64) + seg * 16) =
          *(const float4*)((const char*)&L[hrow + row][0] + seg * 16);
    }
  }
}

extern "C" void kernel_launch(void* const* d_in, const int* in_sizes, int n_in,
                              void* d_out, int out_size, void* d_ws, size_t ws_size,
                              hipStream_t stream) {
  const float* p[30];
  for (int i = 0; i < 30 && i < n_in; ++i) p[i] = (const float*)d_in[i];

  const size_t FEATP = (size_t)NPAD * HD;
  u16* xb  = (u16*)d_ws;
  u16* tmp = xb + FEATP;
  u16* wt  = tmp + FEATP;
  int* cnt    = (int*)(wt + 8 * HD * HD);
  int* bucket = cnt + NODES;

  Params pa;
  pa.x = p[0];
  pa.ei = (const int*)d_in[1];
  const int widx[8] = {2, 8, 10, 16, 18, 24, 26, 28};
  for (int m = 0; m < 8; ++m) {
    pa.ws[m] = p[widx[m]];
    pa.wd[m] = wt + (size_t)m * HD * HD;
  }
  for (int l = 0; l < 3; ++l) {
    const int base = 2 + l * 8;
    pa.b1[l] = p[base + 1]; pa.gg[l] = p[base + 2]; pa.bt[l] = p[base + 3];
    pa.mu[l] = p[base + 4]; pa.vr[l] = p[base + 5]; pa.b2[l] = p[base + 7];
  }
  pa.lb1 = p[27];
  pa.lb2 = p[29];
  pa.xb = xb; pa.tmp = tmp; pa.cnt = cnt; pa.bucket = bucket;
  pa.out = (float*)d_out;

  // ---- guarded cooperative path ----
  static int coop_ok = -1;
  if (coop_ok < 0) {
    int attr = 0;
    hipDeviceGetAttribute(&attr, hipDeviceAttributeCooperativeLaunch, 0);
    int nb = 0;
    hipError_t qe = hipOccupancyMaxActiveBlocksPerMultiprocessor(&nb, gin_all, BLK, 0);
    coop_ok = (attr != 0 && qe == hipSuccess && nb >= 1) ? 1 : 0;
  }
  if (coop_ok) {
    void* args[] = {&pa};
    hipError_t le = hipLaunchCooperativeKernel((void*)gin_all, dim3(GRID),
                                               dim3(BLK), args, 0, stream);
    if (le == hipSuccess) return;
    coop_ok = 0;  // fall through to the verified multi-kernel pipeline
  }

  // ---- fallback: R2-verified pipeline ----
  dim3 blk(256);
  const int edgeGrid = (EDGES + 255) / 256;
  const int gathGrid = NODES / 8;
  const int gemmGrid = NODES / 64;
  WPrep wp;
  for (int m = 0; m < 8; ++m) { wp.s[m] = pa.ws[m]; wp.d[m] = pa.wd[m]; }
  prep_all<<<5285, blk, 0, stream>>>((const float4*)pa.x, (ushort4*)xb, wp, cnt);
  bucket_fill<<<edgeGrid, blk, 0, stream>>>(pa.ei, cnt, bucket);
  for (int l = 0; l < 2; ++l) {
    gather_w<<<gathGrid, blk, 0, stream>>>(xb, cnt, bucket, tmp);
    mlp_fused_k<<<gemmGrid, blk, 0, stream>>>(
        tmp, pa.wd[2 * l], pa.b1[l], pa.gg[l], pa.bt[l], pa.mu[l], pa.vr[l],
        pa.wd[2 * l + 1], pa.b2[l], xb);
  }
  gather_w<<<gathGrid, blk, 0, stream>>>(xb, cnt, bucket, tmp);
  mlp3_head_k<<<gemmGrid, blk, 0, stream>>>(
      tmp, pa.wd[4], pa.b1[2], pa.gg[2], pa.bt[2], pa.mu[2], pa.vr[2],
      pa.wd[5], pa.b2[2], pa.wd[6], pa.lb1, pa.wd[7], pa.lb2, pa.out);
}

// Round 7
// 256.393 us; speedup vs baseline: 1.2055x; 1.0312x over previous
//
#include <hip/hip_runtime.h>
#include <cmath>

#define NODES 40000
#define NPAD  40960            // padded rows: 640 blocks x 64 rows
#define EDGES 600000
#define HD    128
#define CAP   80               // bucket capacity (Poisson mean 15; P(>80) ~ 0)
#define BN_EPS 1e-5f
#define PK    (HD + 8)

typedef short bf16x8 __attribute__((ext_vector_type(8)));
typedef float f32x4  __attribute__((ext_vector_type(4)));
typedef unsigned short u16;
typedef unsigned int   u32;

__device__ __forceinline__ float bf2f(u16 u) {
  union { u32 i; float f; } v; v.i = ((u32)u) << 16; return v.f;
}
__device__ __forceinline__ u16 f2bf(float f) {
  union { float f; u32 i; } v; v.f = f;
  u32 r = v.i + 0x7FFF + ((v.i >> 16) & 1);   // RNE
  return (u16)(r >> 16);
}
__device__ __forceinline__ float elu(float x) {
  return x > 0.f ? x : __expf(x) - 1.f;
}

struct WPrep { const float* s[8]; u16* d[8]; };

// ---------------- one-time prep: cast x | transpose weights | zero cnt -----
__global__ __launch_bounds__(256) void prep_all(const float4* __restrict__ x4,
                                                ushort4* __restrict__ xb4,
                                                WPrep p, int* __restrict__ cnt) {
  const int bid = blockIdx.x;
  const int tid = threadIdx.x;
  if (bid < 5000) {
    int i = bid * 256 + tid;
    float4 v = x4[i];
    ushort4 o;
    o.x = f2bf(v.x); o.y = f2bf(v.y); o.z = f2bf(v.z); o.w = f2bf(v.w);
    xb4[i] = o;
  } else if (bid < 5128) {
    int b = bid - 5000;
    int m = b >> 4, xx = b & 15;
    int N = (m == 7) ? 64 : 128;
    int tiles_n = N / 32;
    int tx = xx % tiles_n, tk = xx / tiles_n;
    if (tk >= 4) return;
    __shared__ float t[32][33];
    int c = tid & 31, r8 = tid >> 5;
    const float* s = p.s[m];
    for (int rr = 0; rr < 32; rr += 8)
      t[rr + r8][c] = s[(size_t)(tk * 32 + rr + r8) * N + tx * 32 + c];
    __syncthreads();
    u16* d = p.d[m];
    for (int rr = 0; rr < 32; rr += 8)
      d[(size_t)(tx * 32 + rr + r8) * HD + tk * 32 + c] = f2bf(t[c][rr + r8]);
  } else {
    int i = (bid - 5128) * 256 + tid;
    if (i < NODES) cnt[i] = 0;
  }
}

// ---------------- bucket fill ----------------
__global__ __launch_bounds__(256) void bucket_fill(const int* __restrict__ ei,
                                                   int* __restrict__ cnt,
                                                   int* __restrict__ bucket) {
  int e = blockIdx.x * 256 + threadIdx.x;
  if (e >= EDGES) return;
  int s = ei[e];
  int d = ei[EDGES + e];
  int pos = atomicAdd(&cnt[d], 1);
  if (pos < CAP) bucket[d * CAP + pos] = s;
}

// ---- in-kernel gather, quarter-wave per node (R6 redesign) ---------------
// R3's fused gather was latency-bound at 2.44 blocks/CU: 8 half-wave chains
// x 2KB outstanding = 39KB/CU in flight. Quarter-wave/node (16 lanes x uint4
// = 256B/row-load) doubles chains to 16/block -> ~80KB/CU outstanding at the
// same block residency, crossing into the bandwidth-limited regime.
// Slots load in 16-entry chunks, broadcast via __shfl(.,.,16); accumulation
// order per dim identical to R2/R3 (bit-identical numerics).
__device__ __forceinline__ void unpack_init(float* a, uint4 v) {
  a[0] = bf2f((u16)v.x); a[1] = bf2f((u16)(v.x >> 16));
  a[2] = bf2f((u16)v.y); a[3] = bf2f((u16)(v.y >> 16));
  a[4] = bf2f((u16)v.z); a[5] = bf2f((u16)(v.z >> 16));
  a[6] = bf2f((u16)v.w); a[7] = bf2f((u16)(v.w >> 16));
}
__device__ __forceinline__ void unpack_add(float* a, uint4 v) {
  a[0] += bf2f((u16)v.x); a[1] += bf2f((u16)(v.x >> 16));
  a[2] += bf2f((u16)v.y); a[3] += bf2f((u16)(v.y >> 16));
  a[4] += bf2f((u16)v.z); a[5] += bf2f((u16)(v.z >> 16));
  a[6] += bf2f((u16)v.w); a[7] += bf2f((u16)(v.w >> 16));
}

__device__ __forceinline__ void gather64(const u16* __restrict__ x,
                                         const int* __restrict__ cnt,
                                         const int* __restrict__ bucket,
                                         int node0, int tid,
                                         u16 (*L)[PK]) {
  const int ql = tid & 15;
  const int qw = tid >> 4;             // 0..15 quarter-waves
  for (int r = 0; r < 4; ++r) {
    const int brow = qw * 4 + r;       // 0..63
    const int node = node0 + brow;
    float a[8];
    if (node < NODES) {
      const int i0 = node * CAP;
      // three independent loads, issued back-to-back
      uint4 self = ((const uint4*)(x + (size_t)node * HD))[ql];
      int sv = bucket[i0 + ql];        // chunk-0 slots (ql<16<=CAP), no cnt dep
      int deg = cnt[node];
      if (deg > CAP) deg = CAP;
      unpack_init(a, self);
      for (int c0 = 0; c0 < deg; c0 += 16) {
        int m = deg - c0;
        if (m > 16) m = 16;
        for (int j = 0; j < m; j += 8) {
          int idx[8];
          uint4 uu[8];
#pragma unroll
          for (int jj = 0; jj < 8; ++jj) {
            int src = j + jj < m ? j + jj : 0;
            idx[jj] = __shfl(sv, src, 16);
          }
#pragma unroll
          for (int jj = 0; jj < 8; ++jj)
            uu[jj] = ((const uint4*)(x + (size_t)idx[jj] * HD))[ql];
#pragma unroll
          for (int jj = 0; jj < 8; ++jj)
            if (j + jj < m) unpack_add(a, uu[jj]);
        }
        int nc = c0 + 16;              // next slot chunk (deg>16); CAP clamp
        if (nc < deg) {
          int ad = nc + ql;
          sv = bucket[i0 + (ad < CAP ? ad : 0)];
        }
      }
    } else {
#pragma unroll
      for (int k = 0; k < 8; ++k) a[k] = 0.f;
    }
    uint4 pk;
    pk.x = (u32)f2bf(a[0]) | ((u32)f2bf(a[1]) << 16);
    pk.y = (u32)f2bf(a[2]) | ((u32)f2bf(a[3]) << 16);
    pk.z = (u32)f2bf(a[4]) | ((u32)f2bf(a[5]) << 16);
    pk.w = (u32)f2bf(a[6]) | ((u32)f2bf(a[7]) << 16);
    *(uint4*)&L[128 + brow][ql * 8] = pk;
  }
}

// ------------- fused layer: gather + ELU(BN(A@W1+b1))@W2+b2, ELU ----------
// LDS rows 0-127: weight (W1, then W2 re-staged); rows 128-191: per-wave
// strips (gathered A, then H). 52224B -> 3 blocks/CU. Grid 640 (64 rows/blk).
__global__ __launch_bounds__(256) void gin_layer(
    const u16* __restrict__ xin, const int* __restrict__ cnt,
    const int* __restrict__ bucket, const u16* __restrict__ W1t,
    const float* __restrict__ b1, const float* __restrict__ g,
    const float* __restrict__ bt, const float* __restrict__ mu,
    const float* __restrict__ vr, const u16* __restrict__ W2t,
    const float* __restrict__ b2, u16* __restrict__ xout) {
  __shared__ u16 L[192][PK];

  const int tid = threadIdx.x;
  const int wv = tid >> 6, lane = tid & 63;
  const int col = lane & 15, kg = lane >> 4;
  const int strip = blockIdx.x * 4 + wv;
  const int hrow = 128 + wv * 16;

  // stage W1 (loads issued first; latency hides under gather)
#pragma unroll
  for (int t = tid; t < 128 * 16; t += 256) {
    int r = t >> 4, c8 = t & 15;
    *(bf16x8*)&L[r][c8 * 8] = *(const bf16x8*)(W1t + (size_t)r * HD + c8 * 8);
  }
  gather64(xin, cnt, bucket, blockIdx.x * 64, tid, L);
  __syncthreads();

  // GEMM1 (A from LDS)
  f32x4 acc[8];
#pragma unroll
  for (int t = 0; t < 8; ++t) acc[t] = (f32x4){0.f, 0.f, 0.f, 0.f};
#pragma unroll
  for (int kk = 0; kk < HD; kk += 32) {
    bf16x8 av = *(const bf16x8*)&L[hrow + col][kk + kg * 8];
#pragma unroll
    for (int t = 0; t < 8; ++t) {
      bf16x8 bv = *(const bf16x8*)&L[t * 16 + col][kk + kg * 8];
      acc[t] = __builtin_amdgcn_mfma_f32_16x16x32_bf16(av, bv, acc[t], 0, 0, 0);
    }
  }
  __syncthreads();  // all waves done reading W1

  // stage W2 into rows 0-127; write H (BN+ELU) over own A strip
#pragma unroll
  for (int t = tid; t < 128 * 16; t += 256) {
    int r = t >> 4, c8 = t & 15;
    *(bf16x8*)&L[r][c8 * 8] = *(const bf16x8*)(W2t + (size_t)r * HD + c8 * 8);
  }
#pragma unroll
  for (int t = 0; t < 8; ++t) {
    int c = t * 16 + col;
    float rs = rsqrtf(vr[c] + BN_EPS) * g[c];
    float bb = bt[c] + (b1[c] - mu[c]) * rs;
#pragma unroll
    for (int r = 0; r < 4; ++r)
      L[hrow + kg * 4 + r][c] = f2bf(elu(acc[t][r] * rs + bb));
  }
  __syncthreads();

  // GEMM2
  f32x4 acc2[8];
#pragma unroll
  for (int t = 0; t < 8; ++t) acc2[t] = (f32x4){0.f, 0.f, 0.f, 0.f};
#pragma unroll
  for (int kk = 0; kk < HD; kk += 32) {
    bf16x8 av = *(const bf16x8*)&L[hrow + col][kk + kg * 8];
#pragma unroll
    for (int t = 0; t < 8; ++t) {
      bf16x8 bv = *(const bf16x8*)&L[t * 16 + col][kk + kg * 8];
      acc2[t] = __builtin_amdgcn_mfma_f32_16x16x32_bf16(av, bv, acc2[t], 0, 0, 0);
    }
  }
#pragma unroll
  for (int t = 0; t < 8; ++t) {
    int c = t * 16 + col;
    float bb = b2[c];
#pragma unroll
    for (int r = 0; r < 4; ++r)
      L[hrow + kg * 4 + r][c] = f2bf(elu(acc2[t][r] + bb));
  }
  {
    int r0 = lane >> 4, seg = lane & 15;
#pragma unroll
    for (int rr = 0; rr < 16; rr += 4) {
      int row = rr + r0;
      *(float4*)((char*)(xout + (size_t)(strip * 16 + row) * HD) + seg * 16) =
          *(const float4*)((const char*)&L[hrow + row][0] + seg * 16);
    }
  }
}

// ---- fused layer-3 + head: gather + 4 chained GEMMs ----------------------
__global__ __launch_bounds__(256) void gin_head(
    const u16* __restrict__ xin, const int* __restrict__ cnt,
    const int* __restrict__ bucket, const u16* __restrict__ W1t,
    const float* __restrict__ b1, const float* __restrict__ g,
    const float* __restrict__ bt, const float* __restrict__ mu,
    const float* __restrict__ vr, const u16* __restrict__ W2t,
    const float* __restrict__ b2, const u16* __restrict__ L1t,
    const float* __restrict__ lb1, const u16* __restrict__ L2t,
    const float* __restrict__ lb2, float* __restrict__ out) {
  __shared__ u16 L[192][PK];

  const int tid = threadIdx.x;
  const int wv = tid >> 6, lane = tid & 63;
  const int col = lane & 15, kg = lane >> 4;
  const int strip = blockIdx.x * 4 + wv;
  const int hrow = 128 + wv * 16;

#pragma unroll
  for (int t = tid; t < 128 * 16; t += 256) {
    int r = t >> 4, c8 = t & 15;
    *(bf16x8*)&L[r][c8 * 8] = *(const bf16x8*)(W1t + (size_t)r * HD + c8 * 8);
  }
  gather64(xin, cnt, bucket, blockIdx.x * 64, tid, L);
  __syncthreads();

  // GEMM1 (BN+ELU)
  f32x4 acc[8];
#pragma unroll
  for (int t = 0; t < 8; ++t) acc[t] = (f32x4){0.f, 0.f, 0.f, 0.f};
#pragma unroll
  for (int kk = 0; kk < HD; kk += 32) {
    bf16x8 av = *(const bf16x8*)&L[hrow + col][kk + kg * 8];
#pragma unroll
    for (int t = 0; t < 8; ++t) {
      bf16x8 bv = *(const bf16x8*)&L[t * 16 + col][kk + kg * 8];
      acc[t] = __builtin_amdgcn_mfma_f32_16x16x32_bf16(av, bv, acc[t], 0, 0, 0);
    }
  }
  __syncthreads();
#pragma unroll
  for (int t = tid; t < 128 * 16; t += 256) {   // stage W2
    int r = t >> 4, c8 = t & 15;
    *(bf16x8*)&L[r][c8 * 8] = *(const bf16x8*)(W2t + (size_t)r * HD + c8 * 8);
  }
#pragma unroll
  for (int t = 0; t < 8; ++t) {
    int c = t * 16 + col;
    float rs = rsqrtf(vr[c] + BN_EPS) * g[c];
    float bb = bt[c] + (b1[c] - mu[c]) * rs;
#pragma unroll
    for (int r = 0; r < 4; ++r)
      L[hrow + kg * 4 + r][c] = f2bf(elu(acc[t][r] * rs + bb));
  }
  __syncthreads();

  // GEMM2 (+b2, ELU)
#pragma unroll
  for (int t = 0; t < 8; ++t) acc[t] = (f32x4){0.f, 0.f, 0.f, 0.f};
#pragma unroll
  for (int kk = 0; kk < HD; kk += 32) {
    bf16x8 av = *(const bf16x8*)&L[hrow + col][kk + kg * 8];
#pragma unroll
    for (int t = 0; t < 8; ++t) {
      bf16x8 bv = *(const bf16x8*)&L[t * 16 + col][kk + kg * 8];
      acc[t] = __builtin_amdgcn_mfma_f32_16x16x32_bf16(av, bv, acc[t], 0, 0, 0);
    }
  }
  __syncthreads();
#pragma unroll
  for (int t = tid; t < 128 * 16; t += 256) {   // stage lin1
    int r = t >> 4, c8 = t & 15;
    *(bf16x8*)&L[r][c8 * 8] = *(const bf16x8*)(L1t + (size_t)r * HD + c8 * 8);
  }
#pragma unroll
  for (int t = 0; t < 8; ++t) {
    int c = t * 16 + col;
    float bb = b2[c];
#pragma unroll
    for (int r = 0; r < 4; ++r)
      L[hrow + kg * 4 + r][c] = f2bf(elu(acc[t][r] + bb));
  }
  __syncthreads();

  // LIN1 (+lb1, ELU)
#pragma unroll
  for (int t = 0; t < 8; ++t) acc[t] = (f32x4){0.f, 0.f, 0.f, 0.f};
#pragma unroll
  for (int kk = 0; kk < HD; kk += 32) {
    bf16x8 av = *(const bf16x8*)&L[hrow + col][kk + kg * 8];
#pragma unroll
    for (int t = 0; t < 8; ++t) {
      bf16x8 bv = *(const bf16x8*)&L[t * 16 + col][kk + kg * 8];
      acc[t] = __builtin_amdgcn_mfma_f32_16x16x32_bf16(av, bv, acc[t], 0, 0, 0);
    }
  }
  __syncthreads();
#pragma unroll
  for (int t = tid; t < 64 * 16; t += 256) {    // stage lin2 (64 rows)
    int r = t >> 4, c8 = t & 15;
    *(bf16x8*)&L[r][c8 * 8] = *(const bf16x8*)(L2t + (size_t)r * HD + c8 * 8);
  }
#pragma unroll
  for (int t = 0; t < 8; ++t) {
    int c = t * 16 + col;
    float bb = lb1[c];
#pragma unroll
    for (int r = 0; r < 4; ++r)
      L[hrow + kg * 4 + r][c] = f2bf(elu(acc[t][r] + bb));
  }
  __syncthreads();

  // LIN2 (+lb2) -> fp32 out [.][64]
  f32x4 acc2[4];
#pragma unroll
  for (int t = 0; t < 4; ++t) acc2[t] = (f32x4){0.f, 0.f, 0.f, 0.f};
#pragma unroll
  for (int kk = 0; kk < HD; kk += 32) {
    bf16x8 av = *(const bf16x8*)&L[hrow + col][kk + kg * 8];
#pragma unroll
    for (int t = 0; t < 4; ++t) {
      bf16x8 bv = *(const bf16x8*)&L[t * 16 + col][kk + kg * 8];
      acc2[t] = __builtin_amdgcn_mfma_f32_16x16x32_bf16(av, bv, acc2[t], 0, 0, 0);
    }
  }
#pragma unroll
  for (int t = 0; t < 4; ++t) {
    int c = t * 16 + col;
    float bb = lb2[c];
#pragma unroll
    for (int r = 0; r < 4; ++r)
      ((float*)&L[hrow + kg * 4 + r][0])[c] = acc2[t][r] + bb;
  }
  if (strip < NODES / 16) {            // real strips only (grid padded)
    int r0 = lane >> 4, seg = lane & 15;
#pragma unroll
    for (int rr = 0; rr < 16; rr += 4) {
      int row = rr + r0;
      *(float4*)((char*)(out + (size_t)(strip * 16 + row) * 64) + seg * 16) =
          *(const float4*)((const char*)&L[hrow + row][0] + seg * 16);
    }
  }
}

extern "C" void kernel_launch(void* const* d_in, const int* in_sizes, int n_in,
                              void* d_out, int out_size, void* d_ws, size_t ws_size,
                              hipStream_t stream) {
  const float* x = (const float*)d_in[0];
  const int* ei  = (const int*)d_in[1];
  const float* p[30];
  for (int i = 0; i < 30 && i < n_in; ++i) p[i] = (const float*)d_in[i];

  const size_t FEATP = (size_t)NPAD * HD;
  u16* xb0  = (u16*)d_ws;
  u16* xb1  = xb0 + FEATP;           // ping-pong
  u16* wt   = xb1 + FEATP;
  u16* wts[8];
  for (int m = 0; m < 8; ++m) wts[m] = wt + (size_t)m * HD * HD;
  int* cnt    = (int*)(wt + 8 * HD * HD);
  int* bucket = cnt + NODES;

  dim3 blk(256);
  const int edgeGrid = (EDGES + 255) / 256;   // 2344
  const int layerGrid = NPAD / 64;            // 640

  WPrep wp;
  const int widx[8] = {2, 8, 10, 16, 18, 24, 26, 28};
  for (int m = 0; m < 8; ++m) { wp.s[m] = p[widx[m]]; wp.d[m] = wts[m]; }
  prep_all<<<5285, blk, 0, stream>>>((const float4*)x, (ushort4*)xb0, wp, cnt);
  bucket_fill<<<edgeGrid, blk, 0, stream>>>(ei, cnt, bucket);

  gin_layer<<<layerGrid, blk, 0, stream>>>(
      xb0, cnt, bucket, wts[0], p[3], p[4], p[5], p[6], p[7], wts[1], p[9], xb1);
  gin_layer<<<layerGrid, blk, 0, stream>>>(
      xb1, cnt, bucket, wts[2], p[11], p[12], p[13], p[14], p[15], wts[3], p[17], xb0);
  gin_head<<<layerGrid, blk, 0, stream>>>(
      xb0, cnt, bucket, wts[4], p[19], p[20], p[21], p[22], p[23], wts[5], p[25],
      wts[6], p[27], wts[7], p[29], (float*)d_out);
}